// Round 3
// baseline (796.978 us; speedup 1.0000x reference)
//
#include <hip/hip_runtime.h>

#define L 2048
#define CIN 16
#define GROUPS 4
#define NEG_INF -1000000000.0f

// ---------------------------------------------------------------------------
// Kernel A: sparsemax tau, one wave per row, Michelot fixed-point iteration.
// tau <- (sum_{z>tau} z - 1)/|{z>tau}|, init tau = max-1 (tau* >= max-1 always,
// so the initial support is a superset; supports are nested => fixed point).
// ---------------------------------------------------------------------------
__global__ __launch_bounds__(256) void tau_kernel(const float* __restrict__ scores,
                                                  float* __restrict__ tau_out) {
    const int wid  = (blockIdx.x << 2) + (threadIdx.x >> 6);
    const int lane = threadIdx.x & 63;
    const int ch   = wid >> 11;
    const int row  = wid & 2047;
    const int n    = row + 1;
    const float* zrow = scores + ((size_t)ch * L + row) * L;

    float v[32];
    float m = NEG_INF;
#pragma unroll
    for (int j = 0; j < 8; ++j) {
        int c4 = lane + (j << 6);
        int c  = c4 << 2;
        float4 z = make_float4(NEG_INF, NEG_INF, NEG_INF, NEG_INF);
        if (c < n) z = *((const float4*)zrow + c4);
        v[4*j+0] = (c + 0 < n) ? z.x : NEG_INF;
        v[4*j+1] = (c + 1 < n) ? z.y : NEG_INF;
        v[4*j+2] = (c + 2 < n) ? z.z : NEG_INF;
        v[4*j+3] = (c + 3 < n) ? z.w : NEG_INF;
        m = fmaxf(m, fmaxf(fmaxf(v[4*j+0], v[4*j+1]), fmaxf(v[4*j+2], v[4*j+3])));
    }
#pragma unroll
    for (int d = 32; d; d >>= 1) m = fmaxf(m, __shfl_xor(m, d, 64));

    float tau = m - 1.0f;
    int k_prev = -1;
    for (int it = 0; it < 64; ++it) {
        float S = 0.0f, Kf = 0.0f;
#pragma unroll
        for (int j = 0; j < 32; ++j) {
            if (v[j] > tau) { S += v[j]; Kf += 1.0f; }
        }
#pragma unroll
        for (int d = 32; d; d >>= 1) {
            S  += __shfl_xor(S,  d, 64);
            Kf += __shfl_xor(Kf, d, 64);
        }
        int K = (int)Kf;
        if (K == k_prev) break;
        tau = (S - 1.0f) / Kf;
        k_prev = K;
    }
    if (lane == 0) tau_out[ch * L + row] = tau;
}

// ---------------------------------------------------------------------------
// Kernel B: grouped 3x3 conv over on-the-fly probs, NO LDS.
// Block = 4 waves; wave = one out-channel; wave covers 256 contiguous cols
// (lane = float4), marches down a 16-row strip with a register-rolling
// 3-row window per input channel. Horizontal neighbors via __shfl; strip
// edge columns via a single exec-masked load (lanes 0 and 63 only).
// The 4 waves read identical input rows -> L1/L2 absorbs the redundancy.
// ---------------------------------------------------------------------------
#define TR 16
#define TCW 256

struct Row6 { float4 v; float lw, rx; };

__global__ __launch_bounds__(256) void conv_kernel(const float* __restrict__ scores,
                                                   const float* __restrict__ tau,
                                                   const float* __restrict__ weight,
                                                   const float* __restrict__ bias,
                                                   float* __restrict__ out) {
    const int c0   = blockIdx.x * TCW;
    const int r0   = blockIdx.y * TR;
    const int g    = blockIdx.z;
    const int t    = threadIdx.x;
    const int o    = __builtin_amdgcn_readfirstlane(t >> 6);   // wave-uniform
    const int lane = t & 63;
    const int go   = g * 4 + o;
    const int c    = c0 + (lane << 2);
    float* outp = out + ((size_t)go * L + r0) * L + c;

    // Tile entirely above the causal diagonal: vectorized zero-fill.
    if (c0 > r0 + TR - 1) {
        const float4 z4 = make_float4(0.f, 0.f, 0.f, 0.f);
#pragma unroll
        for (int rr = 0; rr < TR; ++rr)
            *(float4*)(outp + (size_t)rr * L) = z4;
        return;
    }

    // Weights / bias: wave-uniform addresses -> scalar loads.
    float w[4][9];
#pragma unroll
    for (int i = 0; i < 4; ++i)
#pragma unroll
        for (int k = 0; k < 9; ++k) w[i][k] = weight[(go * 4 + i) * 9 + k];
    const float b = bias[go];

    // Per-channel row loader: probs = max(score - tau[r], 0), causal+bounds masked.
    auto load_row = [&](int i, int r) -> Row6 {
        Row6 R;
        float4 z = make_float4(0.f, 0.f, 0.f, 0.f);
        float ev = 0.f;                       // edge value (lane0: c0-1, lane63: c0+256)
        if (r >= 0 && r < L) {                // uniform branch
            const float tv = tau[(g * 4 + i) * L + r];
            const float* srow = scores + ((size_t)(g * 4 + i) * L + r) * L;
            if (c <= r) {
                float4 zz = *(const float4*)(srow + c);
                z.x = fmaxf(zz.x - tv, 0.f);
                z.y = (c + 1 <= r) ? fmaxf(zz.y - tv, 0.f) : 0.f;
                z.z = (c + 2 <= r) ? fmaxf(zz.z - tv, 0.f) : 0.f;
                z.w = (c + 3 <= r) ? fmaxf(zz.w - tv, 0.f) : 0.f;
            }
            const int ec = (lane == 0) ? (c0 - 1) : (c0 + TCW);
            if ((lane == 0 || lane == 63) && ec >= 0 && ec <= r)
                ev = fmaxf(srow[ec] - tv, 0.f);
        }
        float lw = __shfl_up(z.w, 1, 64);
        float rx = __shfl_down(z.x, 1, 64);
        R.v  = z;
        R.lw = (lane == 0)  ? ev : lw;
        R.rx = (lane == 63) ? ev : rx;
        return R;
    };

    Row6 win[4][3];
#pragma unroll
    for (int i = 0; i < 4; ++i) {
        win[i][0] = load_row(i, r0 - 1);
        win[i][1] = load_row(i, r0);
    }

#pragma unroll
    for (int rr = 0; rr < TR; ++rr) {
#pragma unroll
        for (int i = 0; i < 4; ++i)
            win[i][(rr + 2) % 3] = load_row(i, r0 + rr + 1);

        float4 acc = make_float4(b, b, b, b);
#pragma unroll
        for (int i = 0; i < 4; ++i) {
#pragma unroll
            for (int dy = 0; dy < 3; ++dy) {
                const Row6& R = win[i][(rr + dy) % 3];
                const float w0 = w[i][dy * 3 + 0];
                const float w1 = w[i][dy * 3 + 1];
                const float w2 = w[i][dy * 3 + 2];
                acc.x = fmaf(R.lw,  w0, acc.x);
                acc.x = fmaf(R.v.x, w1, acc.x);
                acc.x = fmaf(R.v.y, w2, acc.x);
                acc.y = fmaf(R.v.x, w0, acc.y);
                acc.y = fmaf(R.v.y, w1, acc.y);
                acc.y = fmaf(R.v.z, w2, acc.y);
                acc.z = fmaf(R.v.y, w0, acc.z);
                acc.z = fmaf(R.v.z, w1, acc.z);
                acc.z = fmaf(R.v.w, w2, acc.z);
                acc.w = fmaf(R.v.z, w0, acc.w);
                acc.w = fmaf(R.v.w, w1, acc.w);
                acc.w = fmaf(R.rx,  w2, acc.w);
            }
        }

        const int r = r0 + rr;
        float4 res;
        res.x = (c     <= r) ? acc.x : 0.f;
        res.y = (c + 1 <= r) ? acc.y : 0.f;
        res.z = (c + 2 <= r) ? acc.z : 0.f;
        res.w = (c + 3 <= r) ? acc.w : 0.f;
        *(float4*)(outp + (size_t)rr * L) = res;
    }
}

extern "C" void kernel_launch(void* const* d_in, const int* in_sizes, int n_in,
                              void* d_out, int out_size, void* d_ws, size_t ws_size,
                              hipStream_t stream) {
    const float* scores = (const float*)d_in[0];
    const float* weight = (const float*)d_in[1];
    const float* bias   = (const float*)d_in[2];
    float* out = (float*)d_out;
    float* tau = (float*)d_ws;                 // 16*2048 floats = 128 KB

    tau_kernel<<<(CIN * L) / 4, 256, 0, stream>>>(scores, tau);

    dim3 gridB(L / TCW, L / TR, GROUPS);
    conv_kernel<<<gridB, 256, 0, stream>>>(scores, tau, weight, bias, out);
}

// Round 4
// 531.185 us; speedup vs baseline: 1.5004x; 1.5004x over previous
//
#include <hip/hip_runtime.h>

#define L 2048
#define CIN 16
#define GROUPS 4
#define NEG_INF  -1000000000.0f
#define POS_THRESH -100000000.0f

// ---------------------------------------------------------------------------
// Kernel A: sparsemax tau, one wave per row, FIXED-COST exact algorithm.
// Support of sparsemax is a subset of C = {z > max-1} (since tau* >= max-1).
// Compact C to lanes (ballot+mbcnt -> per-wave LDS), bitonic-sort 64 lanes
// descending, prefix-sum, k = popcount(1+(i+1)z_i > csum_i  &&  z_i > thresh),
// tau = (csum_{k-1}-1)/k.  Michelot fallback if |C| > 64 (never for Gaussian).
// ---------------------------------------------------------------------------
__global__ __launch_bounds__(256) void tau_kernel(const float* __restrict__ scores,
                                                  float* __restrict__ tau_out) {
    const int wid  = (blockIdx.x << 2) + (threadIdx.x >> 6);
    const int lane = threadIdx.x & 63;
    const int ws   = threadIdx.x >> 6;            // wave slot in block
    const int ch   = wid >> 11;
    const int row  = wid & 2047;
    const int n    = row + 1;
    const float* zrow = scores + ((size_t)ch * L + row) * L;

    float v[32];
    float m = NEG_INF;
#pragma unroll
    for (int j = 0; j < 8; ++j) {
        int c4 = lane + (j << 6);
        int c  = c4 << 2;
        float4 z = make_float4(NEG_INF, NEG_INF, NEG_INF, NEG_INF);
        if (c < n) z = *((const float4*)zrow + c4);
        v[4*j+0] = (c + 0 < n) ? z.x : NEG_INF;
        v[4*j+1] = (c + 1 < n) ? z.y : NEG_INF;
        v[4*j+2] = (c + 2 < n) ? z.z : NEG_INF;
        v[4*j+3] = (c + 3 < n) ? z.w : NEG_INF;
        m = fmaxf(m, fmaxf(fmaxf(v[4*j+0], v[4*j+1]), fmaxf(v[4*j+2], v[4*j+3])));
    }
#pragma unroll
    for (int d = 32; d; d >>= 1) m = fmaxf(m, __shfl_xor(m, d, 64));

    const float thr = m - 1.0f;

    // ---- compact candidates {v > thr} into per-wave LDS buffer ----
    __shared__ float buf[4][64];
    int base = 0;
#pragma unroll
    for (int j = 0; j < 32; ++j) {
        bool p = v[j] > thr;
        unsigned long long mask = __ballot(p);
        if (mask) {
            if (p) {
                int pos = __builtin_amdgcn_mbcnt_lo((unsigned)mask, 0);
                pos = __builtin_amdgcn_mbcnt_hi((unsigned)(mask >> 32), pos);
                pos += base;
                if (pos < 64) buf[ws][pos] = v[j];
            }
            base += __popcll(mask);
        }
    }
    __syncthreads();
    const int cnt = base;

    float tau;
    if (cnt <= 64) {
        float x = (lane < cnt) ? buf[ws][lane] : NEG_INF;
        // bitonic sort, descending across 64 lanes
#pragma unroll
        for (int k = 2; k <= 64; k <<= 1) {
#pragma unroll
            for (int j = k >> 1; j > 0; j >>= 1) {
                float p = __shfl_xor(x, j, 64);
                bool desc    = ((lane & k) == 0);
                bool earlier = ((lane & j) == 0);
                float mx = fmaxf(x, p), mn = fminf(x, p);
                x = (desc == earlier) ? mx : mn;
            }
        }
        // inclusive prefix sum
        float csum = x;
#pragma unroll
        for (int d = 1; d < 64; d <<= 1) {
            float y = __shfl_up(csum, d, 64);
            if (lane >= d) csum += y;
        }
        bool cond = (1.0f + (float)(lane + 1) * x > csum) && (x > POS_THRESH);
        unsigned long long cmask = __ballot(cond);
        int k = (int)__popcll(cmask);             // k >= 1 always (max elem qualifies)
        float ck = __shfl(csum, k - 1, 64);
        tau = (ck - 1.0f) / (float)k;
    } else {
        // Michelot fallback (exact, data-dependent iterations) — cnt>64 is
        // essentially impossible for this input; correctness safety net.
        tau = thr;
        int k_prev = -1;
        for (int it = 0; it < 64; ++it) {
            float S = 0.0f, Kf = 0.0f;
#pragma unroll
            for (int j = 0; j < 32; ++j)
                if (v[j] > tau) { S += v[j]; Kf += 1.0f; }
#pragma unroll
            for (int d = 32; d; d >>= 1) {
                S  += __shfl_xor(S,  d, 64);
                Kf += __shfl_xor(Kf, d, 64);
            }
            int K = (int)Kf;
            if (K == k_prev) break;
            tau = (S - 1.0f) / Kf;
            k_prev = K;
        }
    }
    if (lane == 0) tau_out[ch * L + row] = tau;
}

// ---------------------------------------------------------------------------
// Kernel B: grouped 3x3 conv over on-the-fly probs = max(score - tau, 0).
// Tile 16 rows x 128 cols x 4 oc. Block 256 thr = 4 waves; wave = oc;
// lane = (rowhalf = lane>>5, col4 = lane&31) -> 4 cols x 8 rows of output.
// LDS row layout (stride 132): [0..127] main, [128] right halo (c0+128),
// [131] left halo (c0-1), [129],[130] unused.
// Per (ic,row) window read: ds b128 (main4) + b64 (left pair) + b64 (right
// pair) = 3 LDS ops for 4 outputs. Interior tiles skip all causal/bounds VALU.
// ---------------------------------------------------------------------------
#define TR 16
#define TC 128
#define HR 18
#define PST 132

struct W6 { float l, m0, m1, m2, m3, r; };

__global__ __launch_bounds__(256, 4) void conv_kernel(const float* __restrict__ scores,
                                                      const float* __restrict__ tau,
                                                      const float* __restrict__ weight,
                                                      const float* __restrict__ bias,
                                                      float* __restrict__ out) {
    const int c0 = blockIdx.x * TC;
    const int r0 = blockIdx.y * TR;
    const int g  = blockIdx.z;
    const int t  = threadIdx.x;

    // Fully-dead tile: vectorized zero-fill, no loads.
    if (c0 > r0 + TR - 1) {
        const float4 z4 = make_float4(0.f, 0.f, 0.f, 0.f);
#pragma unroll
        for (int jj = 0; jj < 8; ++jj) {
            int idx = t + (jj << 8);              // 0..2047
            int c4  = idx & 31;
            int r   = (idx >> 5) & 15;
            int o   = idx >> 9;
            float4* p = (float4*)(out + (((size_t)((g << 2) + o) * L + (r0 + r)) * L + c0)) + c4;
            *p = z4;
        }
        return;
    }

    __shared__ __align__(16) float P[4][HR][PST];

    const bool interior = (c0 >= 1) && (c0 + TC + 1 <= r0) && (r0 + TR <= L - 1);

    if (interior) {
        // ---- unchecked staging ----
        for (int ic = 0; ic < 4; ++ic) {
            const float* sb = scores + (size_t)((g << 2) + ic) * L * L;
            const float* tb = tau + ((g << 2) + ic) * L;
#pragma unroll
            for (int kk = 0; kk < 3; ++kk) {
                int idx = t + (kk << 8);
                if (idx < HR * 32) {
                    int hr = idx >> 5;
                    int c4 = idx & 31;
                    int r  = r0 - 1 + hr;
                    float tv = tb[r];
                    float4 z = *((const float4*)(sb + (size_t)r * L + c0) + c4);
                    float4 val;
                    val.x = fmaxf(z.x - tv, 0.f);
                    val.y = fmaxf(z.y - tv, 0.f);
                    val.z = fmaxf(z.z - tv, 0.f);
                    val.w = fmaxf(z.w - tv, 0.f);
                    *((float4*)&P[ic][hr][c4 << 2]) = val;
                }
            }
        }
        if (t < 144) {
            int side = t & 1, j = t >> 1;
            int ic = j / HR, hr = j - ic * HR;
            int r = r0 - 1 + hr;
            int c = side ? (c0 + TC) : (c0 - 1);
            float tv = tau[((g << 2) + ic) * L + r];
            float z  = scores[((size_t)((g << 2) + ic) * L + r) * L + c];
            P[ic][hr][side ? TC : 131] = fmaxf(z - tv, 0.f);
        }
    } else {
        // ---- checked staging (boundary / diagonal tiles) ----
        for (int ic = 0; ic < 4; ++ic) {
            const float* sb = scores + (size_t)((g << 2) + ic) * L * L;
            const float* tb = tau + ((g << 2) + ic) * L;
#pragma unroll
            for (int kk = 0; kk < 3; ++kk) {
                int idx = t + (kk << 8);
                if (idx < HR * 32) {
                    int hr = idx >> 5;
                    int c4 = idx & 31;
                    int r  = r0 - 1 + hr;
                    int cb = c0 + (c4 << 2);
                    float4 val = make_float4(0.f, 0.f, 0.f, 0.f);
                    if (r >= 0 && r < L && cb <= r) {
                        float tv = tb[r];
                        float4 z = *((const float4*)(sb + (size_t)r * L) + (cb >> 2));
                        val.x = fmaxf(z.x - tv, 0.f);
                        val.y = (cb + 1 <= r) ? fmaxf(z.y - tv, 0.f) : 0.f;
                        val.z = (cb + 2 <= r) ? fmaxf(z.z - tv, 0.f) : 0.f;
                        val.w = (cb + 3 <= r) ? fmaxf(z.w - tv, 0.f) : 0.f;
                    }
                    *((float4*)&P[ic][hr][c4 << 2]) = val;
                }
            }
        }
        if (t < 144) {
            int side = t & 1, j = t >> 1;
            int ic = j / HR, hr = j - ic * HR;
            int r = r0 - 1 + hr;
            int c = side ? (c0 + TC) : (c0 - 1);
            float val = 0.f;
            if (r >= 0 && r < L && c >= 0 && c <= r) {
                val = fmaxf(scores[((size_t)((g << 2) + ic) * L + r) * L + c]
                            - tau[((g << 2) + ic) * L + r], 0.f);
            }
            P[ic][hr][side ? TC : 131] = val;
        }
    }
    __syncthreads();

    // ---- compute ----
    const int o    = __builtin_amdgcn_readfirstlane(t >> 6);
    const int lane = t & 63;
    const int col4 = lane & 31;
    const int rh   = lane >> 5;                    // row half: 0 or 1
    const int hb   = rh << 3;                      // staged-row base for this lane
    const int go   = (g << 2) + o;
    const int cb   = c0 + (col4 << 2);
    const int li   = col4 ? ((col4 << 2) - 2) : 130;  // left b64 idx (use .y)
    const int ri   = (col4 << 2) + 4;                 // right b64 idx (use .x)

    float w[4][9];
#pragma unroll
    for (int ic = 0; ic < 4; ++ic)
#pragma unroll
        for (int k = 0; k < 9; ++k) w[ic][k] = weight[((go << 2) + ic) * 9 + k];
    const float bb = bias[go];

    auto ldwin = [&](int ic, int hr) -> W6 {
        const float* rp = &P[ic][hr][0];
        float4 M  = *(const float4*)(rp + (col4 << 2));
        float2 Lv = *(const float2*)(rp + li);
        float2 Rv = *(const float2*)(rp + ri);
        W6 q; q.l = Lv.y; q.m0 = M.x; q.m1 = M.y; q.m2 = M.z; q.m3 = M.w; q.r = Rv.x;
        return q;
    };

    float4 acc[8];
#pragma unroll
    for (int rr = 0; rr < 8; ++rr) acc[rr] = make_float4(bb, bb, bb, bb);

#pragma unroll
    for (int ic = 0; ic < 4; ++ic) {
        W6 a = ldwin(ic, hb);
        W6 b = ldwin(ic, hb + 1);
#pragma unroll
        for (int rr = 0; rr < 8; ++rr) {
            W6 c = ldwin(ic, hb + rr + 2);
            const W6 rows[3] = { a, b, c };
#pragma unroll
            for (int dy = 0; dy < 3; ++dy) {
                const W6& q = rows[dy];
                const float w0 = w[ic][dy * 3 + 0];
                const float w1 = w[ic][dy * 3 + 1];
                const float w2 = w[ic][dy * 3 + 2];
                acc[rr].x = fmaf(q.l,  w0, fmaf(q.m0, w1, fmaf(q.m1, w2, acc[rr].x)));
                acc[rr].y = fmaf(q.m0, w0, fmaf(q.m1, w1, fmaf(q.m2, w2, acc[rr].y)));
                acc[rr].z = fmaf(q.m1, w0, fmaf(q.m2, w1, fmaf(q.m3, w2, acc[rr].z)));
                acc[rr].w = fmaf(q.m2, w0, fmaf(q.m3, w1, fmaf(q.r,  w2, acc[rr].w)));
            }
            a = b; b = c;
        }
    }

    float* outp = out + ((size_t)go * L + (r0 + hb)) * L + cb;
    if (interior) {
#pragma unroll
        for (int rr = 0; rr < 8; ++rr)
            *(float4*)(outp + (size_t)rr * L) = acc[rr];
    } else {
#pragma unroll
        for (int rr = 0; rr < 8; ++rr) {
            int r = r0 + hb + rr;
            float4 res;
            res.x = (cb     <= r) ? acc[rr].x : 0.f;
            res.y = (cb + 1 <= r) ? acc[rr].y : 0.f;
            res.z = (cb + 2 <= r) ? acc[rr].z : 0.f;
            res.w = (cb + 3 <= r) ? acc[rr].w : 0.f;
            *(float4*)(outp + (size_t)rr * L) = res;
        }
    }
}

extern "C" void kernel_launch(void* const* d_in, const int* in_sizes, int n_in,
                              void* d_out, int out_size, void* d_ws, size_t ws_size,
                              hipStream_t stream) {
    const float* scores = (const float*)d_in[0];
    const float* weight = (const float*)d_in[1];
    const float* bias   = (const float*)d_in[2];
    float* out = (float*)d_out;
    float* tau = (float*)d_ws;                 // 16*2048 floats = 128 KB

    tau_kernel<<<(CIN * L) / 4, 256, 0, stream>>>(scores, tau);

    dim3 gridB(L / TC, L / TR, GROUPS);
    conv_kernel<<<gridB, 256, 0, stream>>>(scores, tau, weight, bias, out);
}